// Round 4
// baseline (98333.850 us; speedup 1.0000x reference)
//
#include <hip/hip_runtime.h>

// DARQN: CNN (3 convs) -> per-step attention + 2-layer LSTM (T=2048 sequential) -> Q head.
// Phase B: persistent 16-block x 1024-thread kernel, fence-free tagged-word dataflow.
// R4 change: fix gate-shuffle writer mapping (kd==0 lane writes unit ul; R3 wrote unit tid).
// Hops/step: Dpart-gather(784w), ctx-bcast(256w), h0-bcast(256w), h1-bcast(256w).

#define NB 16
typedef unsigned long long ULL;

__device__ __forceinline__ float fsig(float x) {
  return __builtin_amdgcn_rcpf(1.f + __expf(-x));
}
__device__ __forceinline__ float ftanh(float x) {
  float e = __expf(2.f * x);
  return 1.f - 2.f * __builtin_amdgcn_rcpf(e + 1.f);
}
__device__ __forceinline__ ULL aload(const ULL* p) {
  return __hip_atomic_load(p, __ATOMIC_RELAXED, __HIP_MEMORY_SCOPE_AGENT);
}
__device__ __forceinline__ void astore(ULL* p, ULL v) {
  __hip_atomic_store(p, v, __ATOMIC_RELAXED, __HIP_MEMORY_SCOPE_AGENT);
}
__device__ __forceinline__ ULL pack(unsigned tag, float v) {
  return ((ULL)tag << 32) | (ULL)__float_as_uint(v);
}
__device__ __forceinline__ float poll1(const ULL* p, unsigned tag) {
  ULL v = aload(p);
  while ((unsigned)(v >> 32) != tag) v = aload(p);
  return __uint_as_float((unsigned)v);
}

// ---------------- transpose: out[k*R + r] = in[r*C + k]  (in is [R][C]) ----------------
__global__ void transpose_k(const float* __restrict__ in, float* __restrict__ out, int R, int C) {
  int i = blockIdx.x * 256 + threadIdx.x;
  if (i < R * C) {
    int r = i / C, k = i - r * C;
    out[k * R + r] = in[i];
  }
}

// ---------------- conv1: [T,1,84,84] -> a1[t][c32][p400], 8x8 s4 ----------------
__global__ __launch_bounds__(256) void conv1_k(const float* __restrict__ frames, const float* __restrict__ wT1,
                                               const float* __restrict__ b_c1, float* __restrict__ a1) {
  __shared__ __attribute__((aligned(16))) float fr[7056];
  const int t = blockIdx.x;
  for (int i = threadIdx.x; i < 7056; i += 256) fr[i] = frames[t * 7056 + i];
  __syncthreads();
  const int c = threadIdx.x & 31, pg = threadIdx.x >> 5;
  const int r0 = (pg < 4) ? pg * 3 : 12 + (pg - 4) * 2;
  const int nr = (pg < 4) ? 3 : 2;
  float acc[3][20];
#pragma unroll
  for (int a = 0; a < 3; a++)
#pragma unroll
    for (int o = 0; o < 20; o++) acc[a][o] = 0.f;
  for (int ky = 0; ky < 8; ky++) {
    float w[8];
#pragma unroll
    for (int kx = 0; kx < 8; kx++) w[kx] = wT1[(ky * 8 + kx) * 32 + c];
#pragma unroll
    for (int rr = 0; rr < 3; rr++) {
      if (rr < nr) {
        const float* rowp = &fr[((r0 + rr) * 4 + ky) * 84];
#pragma unroll
        for (int ox = 0; ox < 20; ox++) {
          float4 v0 = *(const float4*)(rowp + ox * 4);
          float4 v1 = *(const float4*)(rowp + ox * 4 + 4);
          acc[rr][ox] += v0.x * w[0] + v0.y * w[1] + v0.z * w[2] + v0.w * w[3]
                       + v1.x * w[4] + v1.y * w[5] + v1.z * w[6] + v1.w * w[7];
        }
      }
    }
  }
  float bias = b_c1[c];
  __syncthreads();
  for (int half = 0; half < 2; half++) {
    if ((c >> 4) == half) {
      int cl = c & 15;
#pragma unroll
      for (int rr = 0; rr < 3; rr++)
        if (rr < nr)
#pragma unroll
          for (int ox = 0; ox < 20; ox++) {
            float vv = acc[rr][ox] + bias;
            fr[cl * 401 + (r0 + rr) * 20 + ox] = vv > 0.f ? vv : 0.f;
          }
    }
    __syncthreads();
    for (int i = threadIdx.x; i < 6400; i += 256) {
      int cl = i / 400, p = i - cl * 400;
      a1[t * 12800 + half * 6400 + i] = fr[cl * 401 + p];
    }
    __syncthreads();
  }
}

// ---------------- conv2: a1[t][32][400] -> a2[t][p81][c64], 4x4 s2 ----------------
__global__ __launch_bounds__(256) void conv2_k(const float* __restrict__ a1, const float* __restrict__ wT2,
                                               const float* __restrict__ b_c2, float* __restrict__ a2) {
  __shared__ __attribute__((aligned(16))) float half_s[6400];
  const int t = blockIdx.x;
  const int c = threadIdx.x & 63, pq = threadIdx.x >> 6;
  const int r0 = (pq == 0) ? 0 : 1 + pq * 2;
  const int nr = (pq == 0) ? 3 : 2;
  float acc[3][9];
#pragma unroll
  for (int a = 0; a < 3; a++)
#pragma unroll
    for (int o = 0; o < 9; o++) acc[a][o] = 0.f;
  for (int ch = 0; ch < 2; ch++) {
    __syncthreads();
    for (int i = threadIdx.x; i < 6400; i += 256) half_s[i] = a1[t * 12800 + ch * 6400 + i];
    __syncthreads();
    for (int ci = 0; ci < 16; ci++) {
#pragma unroll
      for (int ky = 0; ky < 4; ky++) {
        float w[4];
#pragma unroll
        for (int kx = 0; kx < 4; kx++) w[kx] = wT2[(((ch * 16 + ci) * 4 + ky) * 4 + kx) * 64 + c];
#pragma unroll
        for (int rr = 0; rr < 3; rr++) {
          if (rr < nr) {
            const float* rowp = &half_s[ci * 400 + ((r0 + rr) * 2 + ky) * 20];
            float rv[20];
#pragma unroll
            for (int x4 = 0; x4 < 5; x4++) {
              float4 v4 = *(const float4*)(rowp + x4 * 4);
              rv[x4 * 4 + 0] = v4.x; rv[x4 * 4 + 1] = v4.y;
              rv[x4 * 4 + 2] = v4.z; rv[x4 * 4 + 3] = v4.w;
            }
#pragma unroll
            for (int ox = 0; ox < 9; ox++)
#pragma unroll
              for (int kx = 0; kx < 4; kx++)
                acc[rr][ox] += rv[ox * 2 + kx] * w[kx];
          }
        }
      }
    }
  }
  float bias = b_c2[c];
#pragma unroll
  for (int rr = 0; rr < 3; rr++)
    if (rr < nr)
#pragma unroll
      for (int ox = 0; ox < 9; ox++) {
        float vv = acc[rr][ox] + bias;
        a2[t * 5184 + ((r0 + rr) * 9 + ox) * 64 + c] = vv > 0.f ? vv : 0.f;
      }
}

// ---------------- conv3: a2[t][81][64] -> vecs[t][j49][c256], 3x3 s1 ----------------
__global__ __launch_bounds__(256) void conv3_k(const float* __restrict__ a2, const float* __restrict__ wT3,
                                               const float* __restrict__ b_c3, float* __restrict__ vecs) {
  __shared__ __attribute__((aligned(16))) float sm[5184];
  const int t = blockIdx.x;
  const int c = threadIdx.x;
  for (int i = threadIdx.x; i < 5184; i += 256) sm[i] = a2[t * 5184 + i];
  __syncthreads();
  const float4* smv = (const float4*)sm;
  float acc[49];
#pragma unroll
  for (int p = 0; p < 49; p++) acc[p] = 0.f;
  for (int ci4 = 0; ci4 < 16; ci4++) {
#pragma unroll
    for (int ky = 0; ky < 3; ky++) {
      float4 w[3];
#pragma unroll
      for (int kx = 0; kx < 3; kx++) {
        w[kx].x = wT3[((ci4 * 4 + 0) * 9 + ky * 3 + kx) * 256 + c];
        w[kx].y = wT3[((ci4 * 4 + 1) * 9 + ky * 3 + kx) * 256 + c];
        w[kx].z = wT3[((ci4 * 4 + 2) * 9 + ky * 3 + kx) * 256 + c];
        w[kx].w = wT3[((ci4 * 4 + 3) * 9 + ky * 3 + kx) * 256 + c];
      }
#pragma unroll
      for (int oy = 0; oy < 7; oy++) {
        int iy = oy + ky;
        float4 rw[9];
#pragma unroll
        for (int x = 0; x < 9; x++) rw[x] = smv[(iy * 9 + x) * 16 + ci4];
#pragma unroll
        for (int kx = 0; kx < 3; kx++)
#pragma unroll
          for (int ox = 0; ox < 7; ox++) {
            float4 r = rw[ox + kx];
            acc[oy * 7 + ox] += r.x * w[kx].x + r.y * w[kx].y + r.z * w[kx].z + r.w * w[kx].w;
          }
      }
    }
  }
  float bias = b_c3[c];
#pragma unroll
  for (int p = 0; p < 49; p++) {
    float vv = acc[p] + bias;
    vecs[t * 12544 + p * 256 + c] = vv > 0.f ? vv : 0.f;
  }
}

// ---------------- preA[t][j][c] = sum_k vecs[t][j][k]*w_a1[c][k] + b_a1[c] ----------------
__global__ __launch_bounds__(256) void preA_k(const float* __restrict__ vecs, const float* __restrict__ wTa1,
                                              const float* __restrict__ b_a1, float* __restrict__ preA) {
  __shared__ __attribute__((aligned(16))) float lv[12544];
  const int t = blockIdx.x;
  const int c = threadIdx.x;
  for (int i = threadIdx.x; i < 12544; i += 256) lv[i] = vecs[t * 12544 + i];
  __syncthreads();
  const float4* lvv = (const float4*)lv;
  float acc[49];
#pragma unroll
  for (int j = 0; j < 49; j++) acc[j] = 0.f;
  for (int k4 = 0; k4 < 64; k4++) {
    float w0 = wTa1[(k4 * 4 + 0) * 256 + c];
    float w1 = wTa1[(k4 * 4 + 1) * 256 + c];
    float w2 = wTa1[(k4 * 4 + 2) * 256 + c];
    float w3 = wTa1[(k4 * 4 + 3) * 256 + c];
#pragma unroll
    for (int j = 0; j < 49; j++) {
      float4 v4 = lvv[j * 64 + k4];
      acc[j] += v4.x * w0 + v4.y * w1 + v4.z * w2 + v4.w * w3;
    }
  }
  float ba = b_a1[c];
#pragma unroll
  for (int j = 0; j < 49; j++) preA[t * 12544 + j * 256 + c] = acc[j] + ba;
}

// ---------------- sequential scan: 16 blocks x 1024 threads, tagged-word dataflow ----------------
// Block bb owns columns/units [16bb, 16bb+16). P never leaves the block.
// Exchanges per step: Dpart[49][16] gather; ctx[256] bcast; h0[256] bcast; h1[256] bcast.
__global__ __launch_bounds__(1024) void seq_k(
    const float* __restrict__ preA, const float* __restrict__ v,
    const float* __restrict__ w_a2, const float* __restrict__ b_a2,
    const float* __restrict__ w_ih, const float* __restrict__ w_hh,
    const float* __restrict__ b_ih, const float* __restrict__ b_hh,
    const float* __restrict__ w_q, const float* __restrict__ b_q,
    ULL* Dpk, ULL* ctxk, ULL* h0k, ULL* h1k, float* outq) {
  __shared__ __attribute__((aligned(16))) float e_lds[25 * 264];  // two j-phases
  __shared__ __attribute__((aligned(16))) float wa2s[16 * 260];
  __shared__ float ps[784];        // P[j][ci]
  __shared__ float dp_s[16 * 52];  // staged Dparts, transposed [m][j]
  __shared__ float prod[16 * 52];  // ctx partials [ci][j]
  __shared__ float invD[52];
  __shared__ float xs_s[256];
  __shared__ float hs0[256];
  __shared__ float hs1[256];
  __shared__ float red[1024];
  __shared__ float ba2s[16];
  __shared__ float cst0[16];
  __shared__ float cst1[16];

  const int bb = blockIdx.x;
  const int tid = threadIdx.x;
  const int c = tid & 255, jj = tid >> 8;     // alpha tanh mapping
  const int rl = tid & 63, sg = tid >> 6;     // LSTM mapping: 64 gate rows x 16 segs
  const int kd = rl & 3, ul = rl >> 2;
  const int unit = bb * 16 + ul;
  const int row0 = kd * 256 + unit;           // torch gate order i,f,g,o

  // resident LSTM weights: 64 floats/thread
  float wih0r[16], whh0r[16], wih1r[16], whh1r[16];
#pragma unroll
  for (int i = 0; i < 16; i++) {
    wih0r[i] = w_ih[row0 * 256 + sg * 16 + i];
    whh0r[i] = w_hh[row0 * 256 + sg * 16 + i];
    wih1r[i] = w_ih[262144 + row0 * 256 + sg * 16 + i];
    whh1r[i] = w_hh[262144 + row0 * 256 + sg * 16 + i];
  }
  float breg0 = 0.f, breg1 = 0.f;
  if (tid < 64) {
    breg0 = b_ih[row0] + b_hh[row0];
    breg1 = b_ih[1024 + row0] + b_hh[1024 + row0];
  }
  for (int i = tid; i < 4096; i += 1024) {
    int r = i >> 8, k = i & 255;
    wa2s[r * 260 + k] = w_a2[(bb * 16 + r) * 256 + k];
  }
  if (tid < 16) {
    ba2s[tid] = b_a2[bb * 16 + tid];
    cst0[tid] = 0.f;
    cst1[tid] = 0.f;
  }
  if (tid < 256) hs0[tid] = 0.f;

  // preA(0) prefetch: thread owns (j = 4p+jj, c), p=0..12
  float pfA[13];
#pragma unroll
  for (int p = 0; p < 13; p++) {
    int j = 4 * p + jj;
    if (j < 49) pfA[p] = preA[j * 256 + c];
  }
  const int dj = tid >> 4, dci = tid & 15;    // 784-thread (j,ci) mapping
  const int col = bb * 16 + dci;
  __syncthreads();

  for (int t = 0; t < 2048; t++) {
    const unsigned tg = (unsigned)t;
    // ---- v(t) prefetch for beta (register, off critical path) ----
    float vpf = 0.f;
    if (tid < 784) vpf = v[t * 12544 + dj * 256 + col];
    // ======== alpha: e = tanh(preA + h1_prev) [2 phases]; L cols; P; publish Dpart ========
    if (tid < 256) hs1[tid] = poll1(h1k + tid, tg);
    __syncthreads();
    const float h1v = hs1[c];
    // phase 1: j in [0,25)
#pragma unroll
    for (int p = 0; p < 13; p++) {
      int j = 4 * p + jj;
      if (j < 25) e_lds[j * 264 + c] = ftanh(pfA[p] + h1v);
    }
    __syncthreads();
    if (tid < 400) {
      float accL = ba2s[dci];
      const float* er = &e_lds[dj * 264];
      const float* wr = &wa2s[dci * 260];
#pragma unroll 8
      for (int k = 0; k < 256; k += 4) {
        float4 e4 = *(const float4*)(er + k);
        float4 w4 = *(const float4*)(wr + k);
        accL += e4.x * w4.x + e4.y * w4.y + e4.z * w4.z + e4.w * w4.w;
      }
      ps[dj * 16 + dci] = __expf(accL);  // logits small; no max-shift (verified R1/R2)
    }
    __syncthreads();
    // phase 2: j in [25,49)
#pragma unroll
    for (int p = 0; p < 13; p++) {
      int j = 4 * p + jj;
      if (j >= 25 && j < 49) e_lds[(j - 25) * 264 + c] = ftanh(pfA[p] + h1v);
    }
    __syncthreads();
    if (tid < 384) {
      float accL = ba2s[dci];
      const float* er = &e_lds[dj * 264];
      const float* wr = &wa2s[dci * 260];
#pragma unroll 8
      for (int k = 0; k < 256; k += 4) {
        float4 e4 = *(const float4*)(er + k);
        float4 w4 = *(const float4*)(wr + k);
        accL += e4.x * w4.x + e4.y * w4.y + e4.z * w4.z + e4.w * w4.w;
      }
      ps[(25 + dj) * 16 + dci] = __expf(accL);
    }
    // preA(t+1) prefetch (pfA dead after phase-2 tanh)
    if (t < 2047) {
      const float* pA = preA + (t + 1) * 12544;
#pragma unroll
      for (int p = 0; p < 13; p++) {
        int j = 4 * p + jj;
        if (j < 49) pfA[p] = pA[j * 256 + c];
      }
    }
    __syncthreads();
    if (tid < 49) {
      const float* pr = &ps[tid * 16];
      float s = 0.f;
#pragma unroll
      for (int m = 0; m < 16; m++) s += pr[m];
      astore(Dpk + tid * 16 + bb, pack(tg + 1, s));
    }
    // ======== beta: gather Dparts -> invD; ctx cols; publish ctx slice ========
    if (tid < 784) dp_s[dci * 52 + dj] = poll1(Dpk + tid, tg + 1);
    __syncthreads();
    if (tid < 49) {
      float s = 0.f;
#pragma unroll
      for (int m = 0; m < 16; m++) s += dp_s[m * 52 + tid];
      invD[tid] = __builtin_amdgcn_rcpf(s);
    }
    __syncthreads();
    if (tid < 784) prod[dci * 52 + dj] = ps[tid] * invD[dj] * vpf;
    __syncthreads();
    if (tid < 16) {
      const float* pr = &prod[tid * 52];
      float s = 0.f;
#pragma unroll
      for (int j = 0; j < 49; j++) s += pr[j];
      astore(ctxk + bb * 16 + tid, pack(tg + 1, s));
    }
    // ======== gamma: bcast ctx; LSTM layer 0 (16 units); publish h0 slice ========
    if (tid < 256) xs_s[tid] = poll1(ctxk + tid, tg + 1);
    __syncthreads();
    {
      float part = 0.f;
      const float* xp = &xs_s[sg * 16];
      const float* hp = &hs0[sg * 16];
#pragma unroll
      for (int i = 0; i < 16; i++) part += wih0r[i] * xp[i] + whh0r[i] * hp[i];
      red[tid] = part;
    }
    __syncthreads();
    if (tid < 64) {
      float g = breg0;
#pragma unroll
      for (int s2 = 0; s2 < 16; s2++) g += red[s2 * 64 + tid];
      // lane tid = 4*ul+kd holds gate kd of unit ul; pull this unit's 4 gates
      float ig = __shfl(g, ul * 4 + 0), fg = __shfl(g, ul * 4 + 1);
      float gg = __shfl(g, ul * 4 + 2), og = __shfl(g, ul * 4 + 3);
      if (kd == 0) {  // one writer per unit
        float cn = fsig(fg) * cst0[ul] + fsig(ig) * ftanh(gg);
        cst0[ul] = cn;
        astore(h0k + bb * 16 + ul, pack(tg + 1, fsig(og) * ftanh(cn)));
      }
    }
    // ======== delta: bcast h0; LSTM layer 1; publish h1 slice ========
    __syncthreads();  // everyone done reading hs0 before overwrite
    if (tid < 256) hs0[tid] = poll1(h0k + tid, tg + 1);
    __syncthreads();
    {
      float part = 0.f;
      const float* xp = &hs0[sg * 16];
      const float* hp = &hs1[sg * 16];
#pragma unroll
      for (int i = 0; i < 16; i++) part += wih1r[i] * xp[i] + whh1r[i] * hp[i];
      red[tid] = part;
    }
    __syncthreads();  // also: hs1 reads done -> next alpha may overwrite
    if (tid < 64) {
      float g = breg1;
#pragma unroll
      for (int s2 = 0; s2 < 16; s2++) g += red[s2 * 64 + tid];
      float ig = __shfl(g, ul * 4 + 0), fg = __shfl(g, ul * 4 + 1);
      float gg = __shfl(g, ul * 4 + 2), og = __shfl(g, ul * 4 + 3);
      if (kd == 0) {  // one writer per unit
        float cn = fsig(fg) * cst1[ul] + fsig(ig) * ftanh(gg);
        cst1[ul] = cn;
        astore(h1k + bb * 16 + ul, pack(tg + 1, fsig(og) * ftanh(cn)));
      }
    }
  }
  // ======== omega: Q head on final h1 (block 0) ========
  if (bb == 0) {
    if (tid < 256) hs1[tid] = poll1(h1k + tid, 2048u);
    __syncthreads();
    if (tid < 18) {
      float q = b_q[tid];
      const float* wq = w_q + tid * 256;
#pragma unroll 16
      for (int cc = 0; cc < 256; cc++) q += hs1[cc] * wq[cc];
      outq[tid] = q;
    }
  }
}

extern "C" void kernel_launch(void* const* d_in, const int* in_sizes, int n_in,
                              void* d_out, int out_size, void* d_ws, size_t ws_size,
                              hipStream_t stream) {
  const float* frames = (const float*)d_in[0];
  const float* w_c1 = (const float*)d_in[1];
  const float* b_c1 = (const float*)d_in[2];
  const float* w_c2 = (const float*)d_in[3];
  const float* b_c2 = (const float*)d_in[4];
  const float* w_c3 = (const float*)d_in[5];
  const float* b_c3 = (const float*)d_in[6];
  const float* w_a1 = (const float*)d_in[7];
  const float* b_a1 = (const float*)d_in[8];
  const float* w_a2 = (const float*)d_in[9];
  const float* b_a2 = (const float*)d_in[10];
  const float* w_ih = (const float*)d_in[11];
  const float* w_hh = (const float*)d_in[12];
  const float* b_ih = (const float*)d_in[13];
  const float* b_hh = (const float*)d_in[14];
  const float* w_q = (const float*)d_in[15];
  const float* b_q = (const float*)d_in[16];

  float* ws = (float*)d_ws;
  float* wT1 = ws + 16384;      // 2048
  float* wT2 = wT1 + 2048;      // 32768
  float* wT3 = wT2 + 32768;     // 147456
  float* wTa1 = wT3 + 147456;   // 65536
  float* region0 = wTa1 + 65536;        // a1 (26214400 fl), later vecs (25690112 fl)
  float* a1 = region0;
  float* vecs = region0;
  float* a2 = region0 + 26214400;       // later preA (25690112 fl)
  float* preA = a2;

  // comm block in region0 tail (a1 tail, dead after conv2):
  // Dpk[784] ctxk[256] h0k[256] h1k[256] = 1552 ull = 12416 B
  ULL* comm = (ULL*)(region0 + 25690112);
  ULL* Dpk = comm;
  ULL* ctxk = comm + 784;
  ULL* h0k = comm + 1040;
  ULL* h1k = comm + 1296;

  transpose_k<<<8, 256, 0, stream>>>(w_c1, wT1, 32, 64);
  transpose_k<<<128, 256, 0, stream>>>(w_c2, wT2, 64, 512);
  transpose_k<<<576, 256, 0, stream>>>(w_c3, wT3, 256, 576);
  transpose_k<<<256, 256, 0, stream>>>(w_a1, wTa1, 256, 256);

  conv1_k<<<2048, 256, 0, stream>>>(frames, wT1, b_c1, a1);
  conv2_k<<<2048, 256, 0, stream>>>(a1, wT2, b_c2, a2);
  conv3_k<<<2048, 256, 0, stream>>>(a2, wT3, b_c3, vecs);
  preA_k<<<2048, 256, 0, stream>>>(vecs, wTa1, b_a1, preA);

  // zero tags (stream-ordered after conv2 consumed a1; tag0 h1 payload = zeros)
  hipMemsetAsync(comm, 0, 1552 * sizeof(ULL), stream);

  seq_k<<<NB, 1024, 0, stream>>>(preA, vecs, w_a2, b_a2, w_ih, w_hh, b_ih, b_hh,
                                 w_q, b_q, Dpk, ctxk, h0k, h1k, (float*)d_out);
}

// Round 5
// 30767.813 us; speedup vs baseline: 3.1960x; 3.1960x over previous
//
#include <hip/hip_runtime.h>

// DARQN: CNN (3 convs) -> per-step attention + 2-layer LSTM (T=2048 sequential) -> Q head.
// Phase B: persistent 64-block x 256-thread kernel (R2 shape: VGPR-resident LSTM weights,
// no spill), fence-free tagged-word dataflow. R5: drop R2's useless P-matrix poll (6.4MB/step)
// and vv[49] column loads; per-thread ctx term uses the locally computed p register.
// Hops/step: Dpart(49w publish / 3136w poll), ctx(4w/256w), h0(4w/256w), h1(4w/256w).

#define NB 64
typedef unsigned long long ULL;

__device__ __forceinline__ float fsig(float x) {
  return __builtin_amdgcn_rcpf(1.f + __expf(-x));
}
__device__ __forceinline__ float ftanh(float x) {
  float e = __expf(2.f * x);
  return 1.f - 2.f * __builtin_amdgcn_rcpf(e + 1.f);
}
__device__ __forceinline__ ULL aload(const ULL* p) {
  return __hip_atomic_load(p, __ATOMIC_RELAXED, __HIP_MEMORY_SCOPE_AGENT);
}
__device__ __forceinline__ void astore(ULL* p, ULL v) {
  __hip_atomic_store(p, v, __ATOMIC_RELAXED, __HIP_MEMORY_SCOPE_AGENT);
}
__device__ __forceinline__ ULL pack(unsigned tag, float v) {
  return ((ULL)tag << 32) | (ULL)__float_as_uint(v);
}
__device__ __forceinline__ float poll1(const ULL* p, unsigned tag) {
  ULL v = aload(p);
  while ((unsigned)(v >> 32) != tag) {
    __builtin_amdgcn_s_sleep(1);
    v = aload(p);
  }
  return __uint_as_float((unsigned)v);
}

// ---------------- transpose: out[k*R + r] = in[r*C + k]  (in is [R][C]) ----------------
__global__ void transpose_k(const float* __restrict__ in, float* __restrict__ out, int R, int C) {
  int i = blockIdx.x * 256 + threadIdx.x;
  if (i < R * C) {
    int r = i / C, k = i - r * C;
    out[k * R + r] = in[i];
  }
}

// ---------------- conv1: [T,1,84,84] -> a1[t][c32][p400], 8x8 s4 ----------------
__global__ __launch_bounds__(256) void conv1_k(const float* __restrict__ frames, const float* __restrict__ wT1,
                                               const float* __restrict__ b_c1, float* __restrict__ a1) {
  __shared__ __attribute__((aligned(16))) float fr[7056];
  const int t = blockIdx.x;
  for (int i = threadIdx.x; i < 7056; i += 256) fr[i] = frames[t * 7056 + i];
  __syncthreads();
  const int c = threadIdx.x & 31, pg = threadIdx.x >> 5;
  const int r0 = (pg < 4) ? pg * 3 : 12 + (pg - 4) * 2;
  const int nr = (pg < 4) ? 3 : 2;
  float acc[3][20];
#pragma unroll
  for (int a = 0; a < 3; a++)
#pragma unroll
    for (int o = 0; o < 20; o++) acc[a][o] = 0.f;
  for (int ky = 0; ky < 8; ky++) {
    float w[8];
#pragma unroll
    for (int kx = 0; kx < 8; kx++) w[kx] = wT1[(ky * 8 + kx) * 32 + c];
#pragma unroll
    for (int rr = 0; rr < 3; rr++) {
      if (rr < nr) {
        const float* rowp = &fr[((r0 + rr) * 4 + ky) * 84];
#pragma unroll
        for (int ox = 0; ox < 20; ox++) {
          float4 v0 = *(const float4*)(rowp + ox * 4);
          float4 v1 = *(const float4*)(rowp + ox * 4 + 4);
          acc[rr][ox] += v0.x * w[0] + v0.y * w[1] + v0.z * w[2] + v0.w * w[3]
                       + v1.x * w[4] + v1.y * w[5] + v1.z * w[6] + v1.w * w[7];
        }
      }
    }
  }
  float bias = b_c1[c];
  __syncthreads();
  for (int half = 0; half < 2; half++) {
    if ((c >> 4) == half) {
      int cl = c & 15;
#pragma unroll
      for (int rr = 0; rr < 3; rr++)
        if (rr < nr)
#pragma unroll
          for (int ox = 0; ox < 20; ox++) {
            float vv = acc[rr][ox] + bias;
            fr[cl * 401 + (r0 + rr) * 20 + ox] = vv > 0.f ? vv : 0.f;
          }
    }
    __syncthreads();
    for (int i = threadIdx.x; i < 6400; i += 256) {
      int cl = i / 400, p = i - cl * 400;
      a1[t * 12800 + half * 6400 + i] = fr[cl * 401 + p];
    }
    __syncthreads();
  }
}

// ---------------- conv2: a1[t][32][400] -> a2[t][p81][c64], 4x4 s2 ----------------
__global__ __launch_bounds__(256) void conv2_k(const float* __restrict__ a1, const float* __restrict__ wT2,
                                               const float* __restrict__ b_c2, float* __restrict__ a2) {
  __shared__ __attribute__((aligned(16))) float half_s[6400];
  const int t = blockIdx.x;
  const int c = threadIdx.x & 63, pq = threadIdx.x >> 6;
  const int r0 = (pq == 0) ? 0 : 1 + pq * 2;
  const int nr = (pq == 0) ? 3 : 2;
  float acc[3][9];
#pragma unroll
  for (int a = 0; a < 3; a++)
#pragma unroll
    for (int o = 0; o < 9; o++) acc[a][o] = 0.f;
  for (int ch = 0; ch < 2; ch++) {
    __syncthreads();
    for (int i = threadIdx.x; i < 6400; i += 256) half_s[i] = a1[t * 12800 + ch * 6400 + i];
    __syncthreads();
    for (int ci = 0; ci < 16; ci++) {
#pragma unroll
      for (int ky = 0; ky < 4; ky++) {
        float w[4];
#pragma unroll
        for (int kx = 0; kx < 4; kx++) w[kx] = wT2[(((ch * 16 + ci) * 4 + ky) * 4 + kx) * 64 + c];
#pragma unroll
        for (int rr = 0; rr < 3; rr++) {
          if (rr < nr) {
            const float* rowp = &half_s[ci * 400 + ((r0 + rr) * 2 + ky) * 20];
            float rv[20];
#pragma unroll
            for (int x4 = 0; x4 < 5; x4++) {
              float4 v4 = *(const float4*)(rowp + x4 * 4);
              rv[x4 * 4 + 0] = v4.x; rv[x4 * 4 + 1] = v4.y;
              rv[x4 * 4 + 2] = v4.z; rv[x4 * 4 + 3] = v4.w;
            }
#pragma unroll
            for (int ox = 0; ox < 9; ox++)
#pragma unroll
              for (int kx = 0; kx < 4; kx++)
                acc[rr][ox] += rv[ox * 2 + kx] * w[kx];
          }
        }
      }
    }
  }
  float bias = b_c2[c];
#pragma unroll
  for (int rr = 0; rr < 3; rr++)
    if (rr < nr)
#pragma unroll
      for (int ox = 0; ox < 9; ox++) {
        float vv = acc[rr][ox] + bias;
        a2[t * 5184 + ((r0 + rr) * 9 + ox) * 64 + c] = vv > 0.f ? vv : 0.f;
      }
}

// ---------------- conv3: a2[t][81][64] -> vecs[t][j49][c256], 3x3 s1 ----------------
__global__ __launch_bounds__(256) void conv3_k(const float* __restrict__ a2, const float* __restrict__ wT3,
                                               const float* __restrict__ b_c3, float* __restrict__ vecs) {
  __shared__ __attribute__((aligned(16))) float sm[5184];
  const int t = blockIdx.x;
  const int c = threadIdx.x;
  for (int i = threadIdx.x; i < 5184; i += 256) sm[i] = a2[t * 5184 + i];
  __syncthreads();
  const float4* smv = (const float4*)sm;
  float acc[49];
#pragma unroll
  for (int p = 0; p < 49; p++) acc[p] = 0.f;
  for (int ci4 = 0; ci4 < 16; ci4++) {
#pragma unroll
    for (int ky = 0; ky < 3; ky++) {
      float4 w[3];
#pragma unroll
      for (int kx = 0; kx < 3; kx++) {
        w[kx].x = wT3[((ci4 * 4 + 0) * 9 + ky * 3 + kx) * 256 + c];
        w[kx].y = wT3[((ci4 * 4 + 1) * 9 + ky * 3 + kx) * 256 + c];
        w[kx].z = wT3[((ci4 * 4 + 2) * 9 + ky * 3 + kx) * 256 + c];
        w[kx].w = wT3[((ci4 * 4 + 3) * 9 + ky * 3 + kx) * 256 + c];
      }
#pragma unroll
      for (int oy = 0; oy < 7; oy++) {
        int iy = oy + ky;
        float4 rw[9];
#pragma unroll
        for (int x = 0; x < 9; x++) rw[x] = smv[(iy * 9 + x) * 16 + ci4];
#pragma unroll
        for (int kx = 0; kx < 3; kx++)
#pragma unroll
          for (int ox = 0; ox < 7; ox++) {
            float4 r = rw[ox + kx];
            acc[oy * 7 + ox] += r.x * w[kx].x + r.y * w[kx].y + r.z * w[kx].z + r.w * w[kx].w;
          }
      }
    }
  }
  float bias = b_c3[c];
#pragma unroll
  for (int p = 0; p < 49; p++) {
    float vv = acc[p] + bias;
    vecs[t * 12544 + p * 256 + c] = vv > 0.f ? vv : 0.f;
  }
}

// ---------------- preA[t][j][c] = sum_k vecs[t][j][k]*w_a1[c][k] + b_a1[c] ----------------
__global__ __launch_bounds__(256) void preA_k(const float* __restrict__ vecs, const float* __restrict__ wTa1,
                                              const float* __restrict__ b_a1, float* __restrict__ preA) {
  __shared__ __attribute__((aligned(16))) float lv[12544];
  const int t = blockIdx.x;
  const int c = threadIdx.x;
  for (int i = threadIdx.x; i < 12544; i += 256) lv[i] = vecs[t * 12544 + i];
  __syncthreads();
  const float4* lvv = (const float4*)lv;
  float acc[49];
#pragma unroll
  for (int j = 0; j < 49; j++) acc[j] = 0.f;
  for (int k4 = 0; k4 < 64; k4++) {
    float w0 = wTa1[(k4 * 4 + 0) * 256 + c];
    float w1 = wTa1[(k4 * 4 + 1) * 256 + c];
    float w2 = wTa1[(k4 * 4 + 2) * 256 + c];
    float w3 = wTa1[(k4 * 4 + 3) * 256 + c];
#pragma unroll
    for (int j = 0; j < 49; j++) {
      float4 v4 = lvv[j * 64 + k4];
      acc[j] += v4.x * w0 + v4.y * w1 + v4.z * w2 + v4.w * w3;
    }
  }
  float ba = b_a1[c];
#pragma unroll
  for (int j = 0; j < 49; j++) preA[t * 12544 + j * 256 + c] = acc[j] + ba;
}

// ---------------- sequential scan: 64 blocks x 256 threads, tagged-word dataflow ----------------
// Block b owns columns/units [4b, 4b+4). Tags: Dpart published at alpha(t) with tag t+1;
// ctx at beta(t) tag t+1; h0 at gamma(t) tag t+1; h1 at delta(t) tag t+1 (alpha(t) polls tag t).
__global__ __launch_bounds__(256, 1) void seq_k(
    const float* __restrict__ preA, const float* __restrict__ v,
    const float* __restrict__ w_a2, const float* __restrict__ b_a2,
    const float* __restrict__ w_ih, const float* __restrict__ w_hh,
    const float* __restrict__ b_ih, const float* __restrict__ b_hh,
    const float* __restrict__ w_q, const float* __restrict__ b_q,
    ULL* Dpk, ULL* ctxk, ULL* h0k, ULL* h1k, float* outq) {
  __shared__ __attribute__((aligned(16))) float e_lds[49 * 260];
  __shared__ __attribute__((aligned(16))) float wa2s[4 * 260];
  __shared__ float invD[49];
  __shared__ float red[256];
  __shared__ float xs_s[256];
  __shared__ float hs0[256];
  __shared__ float hs1[256];
  __shared__ float gate_s[16];
  __shared__ float cst[8];

  const int b = blockIdx.x;
  const int tid = threadIdx.x;
  const int b4 = b * 4;
  const int gi = tid & 15, seg = tid >> 4;
  const int u_loc = gi >> 2, kd = gi & 3;
  const int row = kd * 256 + b4 + u_loc;  // torch gate order i,f,g,o

  // resident LSTM weight fragments (registers, 64 floats/thread; VGPR~256, no spill at 256thr)
  float wih0r[16], whh0r[16], wih1r[16], whh1r[16];
#pragma unroll
  for (int i = 0; i < 16; i++) {
    wih0r[i] = w_ih[row * 256 + seg * 16 + i];
    whh0r[i] = w_hh[row * 256 + seg * 16 + i];
    wih1r[i] = w_ih[262144 + row * 256 + seg * 16 + i];
    whh1r[i] = w_hh[262144 + row * 256 + seg * 16 + i];
  }
  float breg0 = 0.f, breg1 = 0.f;
  if (tid < 16) {
    int rowt = (tid & 3) * 256 + b4 + (tid >> 2);
    breg0 = b_ih[rowt] + b_hh[rowt];
    breg1 = b_ih[1024 + rowt] + b_hh[1024 + rowt];
  }
  // resident w_a2 slice (4 rows), padded stride 260
  for (int i = tid; i < 1024; i += 256) {
    int r = i >> 8, k = i & 255;
    wa2s[r * 260 + k] = w_a2[(b4 + r) * 256 + k];
  }
  const float ba2r = b_a2[b4 + (tid & 3)];
  if (tid < 8) cst[tid] = 0.f;
  hs0[tid] = 0.f;  // h0_prev for t=0

  // preA(0) prefetch: thread owns column c=tid, all 49 j
  float pfA[49];
#pragma unroll
  for (int k = 0; k < 49; k++) pfA[k] = preA[k * 256 + tid];

  const int j2 = tid >> 2, ci = tid & 3;
  const int w_id = tid >> 6, lane = tid & 63;
  __syncthreads();

  for (int t = 0; t < 2048; t++) {
    const unsigned tg = (unsigned)t;
    // v(t) prefetch: one value/thread, needed only by (j2<49) threads in beta
    float vpf = (j2 < 49) ? v[t * 12544 + j2 * 256 + b4 + ci] : 0.f;
    // ======== alpha: e = tanh(preA + h1_prev); L slice; P; publish Dpart ========
    float h1v = poll1(h1k + tid, tg);
    hs1[tid] = h1v;
#pragma unroll
    for (int j = 0; j < 49; j++) e_lds[j * 260 + tid] = ftanh(pfA[j] + h1v);
    __syncthreads();
    float p = 0.f;
    if (j2 < 49) {
      float accL = ba2r;
      const float* er = &e_lds[j2 * 260];
      const float* wr = &wa2s[ci * 260];
#pragma unroll 8
      for (int k = 0; k < 256; k += 4) {
        float4 e4 = *(const float4*)(er + k);
        float4 w4 = *(const float4*)(wr + k);
        accL += e4.x * w4.x + e4.y * w4.y + e4.z * w4.z + e4.w * w4.w;
      }
      p = __expf(accL);  // logits small; no max-shift needed (verified R1/R2)
    }
    float pq = p + __shfl_xor(p, 1);
    pq += __shfl_xor(pq, 2);
    if (j2 < 49 && ci == 0) astore(Dpk + j2 * 64 + b, pack(tg + 1, pq));

    // ======== beta: poll Dparts; invD; ctx slice from local p; publish ctx ========
    float dpv[13];
    {
      unsigned have = 0;
      const unsigned need = (tid < 64) ? 0x1FFFu : 0xFFFu;
      while (have != need) {
        ULL cur[13];
#pragma unroll
        for (int m = 0; m < 13; m++)
          if ((tid + 256 * m < 3136) && !((have >> m) & 1)) cur[m] = aload(Dpk + tid + 256 * m);
#pragma unroll
        for (int m = 0; m < 13; m++)
          if ((tid + 256 * m < 3136) && !((have >> m) & 1) && (unsigned)(cur[m] >> 32) == tg + 1u) {
            dpv[m] = __uint_as_float((unsigned)cur[m]);
            have |= (1u << m);
          }
        if (have != need) __builtin_amdgcn_s_sleep(1);
      }
    }
    // D_j: holders of row j are the 64 lanes of wave (j%4), slot m=j>>2 -> butterfly
#pragma unroll
    for (int m = 0; m < 13; m++) {
      int j = 4 * m + w_id;
      float d = (tid + 256 * m < 3136) ? dpv[m] : 0.f;
      d += __shfl_xor(d, 1);  d += __shfl_xor(d, 2);  d += __shfl_xor(d, 4);
      d += __shfl_xor(d, 8);  d += __shfl_xor(d, 16); d += __shfl_xor(d, 32);
      if (j < 49 && lane == 0) invD[j] = __builtin_amdgcn_rcpf(d);
    }
    __syncthreads();
    red[tid] = (j2 < 49) ? p * invD[j2] * vpf : 0.f;
    __syncthreads();
    if (tid < 4) {
      float s = 0.f;
      for (int j = 0; j < 49; j++) s += red[j * 4 + tid];
      astore(ctxk + b4 + tid, pack(tg + 1, s));
    }
    // ======== gamma: poll ctx; LSTM layer 0; publish h0 slice ========
    xs_s[tid] = poll1(ctxk + tid, tg + 1);
    __syncthreads();
    {
      float part = 0.f;
      const float* xp = &xs_s[seg * 16];
      const float* hp = &hs0[seg * 16];
#pragma unroll
      for (int i = 0; i < 16; i++) part += wih0r[i] * xp[i] + whh0r[i] * hp[i];
      red[tid] = part;
    }
    __syncthreads();
    if (tid < 16) {
      float g = breg0;
#pragma unroll
      for (int s2 = 0; s2 < 16; s2++) g += red[s2 * 16 + tid];
      gate_s[tid] = g;
    }
    __syncthreads();
    if (tid < 4) {
      float ig = gate_s[tid * 4 + 0], fg = gate_s[tid * 4 + 1];
      float gg = gate_s[tid * 4 + 2], og = gate_s[tid * 4 + 3];
      float cn = fsig(fg) * cst[tid] + fsig(ig) * ftanh(gg);
      cst[tid] = cn;
      astore(h0k + b4 + tid, pack(tg + 1, fsig(og) * ftanh(cn)));
    }
    // preA(t+1) prefetch (off critical path: hides HBM latency behind delta + next alpha)
    if (t < 2047) {
      const float* pA = preA + (t + 1) * 12544;
#pragma unroll
      for (int k = 0; k < 49; k++) pfA[k] = pA[k * 256 + tid];
    }

    // ======== delta: poll h0; LSTM layer 1; publish h1 slice ========
    float h0n = poll1(h0k + tid, tg + 1);
    hs0[tid] = h0n;  // also h0_prev for gamma(t+1)
    __syncthreads();
    {
      float part = 0.f;
      const float* xp = &hs0[seg * 16];
      const float* hp = &hs1[seg * 16];
#pragma unroll
      for (int i = 0; i < 16; i++) part += wih1r[i] * xp[i] + whh1r[i] * hp[i];
      red[tid] = part;
    }
    __syncthreads();
    if (tid < 16) {
      float g = breg1;
#pragma unroll
      for (int s2 = 0; s2 < 16; s2++) g += red[s2 * 16 + tid];
      gate_s[tid] = g;
    }
    __syncthreads();
    if (tid < 4) {
      float ig = gate_s[tid * 4 + 0], fg = gate_s[tid * 4 + 1];
      float gg = gate_s[tid * 4 + 2], og = gate_s[tid * 4 + 3];
      float cn = fsig(fg) * cst[4 + tid] + fsig(ig) * ftanh(gg);
      cst[4 + tid] = cn;
      astore(h1k + b4 + tid, pack(tg + 1, fsig(og) * ftanh(cn)));
    }
  }
  // ======== omega: Q head on final h1 (block 0) ========
  if (b == 0) {
    hs1[tid] = poll1(h1k + tid, 2048u);
    __syncthreads();
    if (tid < 18) {
      float q = b_q[tid];
      const float* wq = w_q + tid * 256;
#pragma unroll 16
      for (int cc = 0; cc < 256; cc++) q += hs1[cc] * wq[cc];
      outq[tid] = q;
    }
  }
}

extern "C" void kernel_launch(void* const* d_in, const int* in_sizes, int n_in,
                              void* d_out, int out_size, void* d_ws, size_t ws_size,
                              hipStream_t stream) {
  const float* frames = (const float*)d_in[0];
  const float* w_c1 = (const float*)d_in[1];
  const float* b_c1 = (const float*)d_in[2];
  const float* w_c2 = (const float*)d_in[3];
  const float* b_c2 = (const float*)d_in[4];
  const float* w_c3 = (const float*)d_in[5];
  const float* b_c3 = (const float*)d_in[6];
  const float* w_a1 = (const float*)d_in[7];
  const float* b_a1 = (const float*)d_in[8];
  const float* w_a2 = (const float*)d_in[9];
  const float* b_a2 = (const float*)d_in[10];
  const float* w_ih = (const float*)d_in[11];
  const float* w_hh = (const float*)d_in[12];
  const float* b_ih = (const float*)d_in[13];
  const float* b_hh = (const float*)d_in[14];
  const float* w_q = (const float*)d_in[15];
  const float* b_q = (const float*)d_in[16];

  float* ws = (float*)d_ws;
  float* wT1 = ws + 16384;      // 2048
  float* wT2 = wT1 + 2048;      // 32768
  float* wT3 = wT2 + 32768;     // 147456
  float* wTa1 = wT3 + 147456;   // 65536
  float* region0 = wTa1 + 65536;        // a1 (26214400 fl), later vecs (25690112 fl)
  float* a1 = region0;
  float* vecs = region0;
  float* a2 = region0 + 26214400;       // later preA (25690112 fl)
  float* preA = a2;

  // comm block in region0 tail (a1 tail, dead after conv2):
  // Dpk[3136] ctxk[256] h0k[256] h1k[256] = 3904 ull = 31232 B
  ULL* comm = (ULL*)(region0 + 25690112);
  ULL* Dpk = comm;
  ULL* ctxk = comm + 3136;
  ULL* h0k = comm + 3392;
  ULL* h1k = comm + 3648;

  transpose_k<<<8, 256, 0, stream>>>(w_c1, wT1, 32, 64);
  transpose_k<<<128, 256, 0, stream>>>(w_c2, wT2, 64, 512);
  transpose_k<<<576, 256, 0, stream>>>(w_c3, wT3, 256, 576);
  transpose_k<<<256, 256, 0, stream>>>(w_a1, wTa1, 256, 256);

  conv1_k<<<2048, 256, 0, stream>>>(frames, wT1, b_c1, a1);
  conv2_k<<<2048, 256, 0, stream>>>(a1, wT2, b_c2, a2);
  conv3_k<<<2048, 256, 0, stream>>>(a2, wT3, b_c3, vecs);
  preA_k<<<2048, 256, 0, stream>>>(vecs, wTa1, b_a1, preA);

  // zero tags (stream-ordered after conv2 consumed a1; tag0 h1 payload = zeros)
  hipMemsetAsync(comm, 0, 3904 * sizeof(ULL), stream);

  seq_k<<<NB, 256, 0, stream>>>(preA, vecs, w_a2, b_a2, w_ih, w_hh, b_ih, b_hh,
                                w_q, b_q, Dpk, ctxk, h0k, h1k, (float*)d_out);
}